// Round 8
// baseline (473.956 us; speedup 1.0000x reference)
//
#include <hip/hip_runtime.h>
#include <hip/hip_bf16.h>

typedef __attribute__((ext_vector_type(8))) short short8;
typedef __attribute__((ext_vector_type(4))) short short4v;
typedef __attribute__((ext_vector_type(4))) float floatx4;

#define N_CELLS  500000
#define B_SAMP   512
#define D_X      128
#define D_Z      32
#define H_DIM    256
#define D_OUT    16

#define M_TILE   96
#define NBLK     5209          // ceil(500000/96); last block has 32 valid cells
#define LDA      128           // xp row stride (shorts), pow2 + XOR swizzle
#define LDH      256           // sH row stride (shorts), pow2 + XOR swizzle
#define SP_LD    20            // GEMM3 partial row stride (f32)

// XOR swizzle: flips 16B-block bits of the short-index by row&7.
// All writes are >=4-short aligned, reads 8-short aligned -> alignment-safe.
#define SWZ(c, r) ((c) ^ (((r) & 7) << 3))

#define NREP     64

// workspace layout (bytes), 16B aligned
#define OFF_W1P   0            // 16*4*512*2   = 65536
#define OFF_W2P   65536        // 16*8*512*2   = 131072
#define OFF_W3P   196608       // 1*8*512*2    = 8192
#define OFF_ZW    204800       // 512*256*4    = 524288
#define OFF_ACC   729088       // 64*8192*4    = 2097152
#define OFF_CNT   2826240      // 64*512*4     = 131072
#define OFF_C2S   2957312      // 500000*4     = 2000000

#define W1_BLKS   128
#define W2_BLKS   256
#define W3_BLKS   16
#define ZW_BLKS   512
#define C2S_BLKS  1954

__device__ __forceinline__ short bfb(float x) {
    union { __hip_bfloat16 h; short s; } u;
    u.h = __float2bfloat16(x);
    return u.s;
}

// prep: pack W1(K=128, ln2-folded)/W2/W3 into MFMA fragment order;
// ZW1[b][n] = Z[b,:]@W1[128:160,n] + b1[n]; c2s[cell]=sidx[c2b[cell]];
// counts histogram (MLP-independent) into replicated cnts.
// accs/cnts zeroed by hipMemsetAsync before this launch.
__global__ __launch_bounds__(256)
void prep(const float* __restrict__ W1, const float* __restrict__ b1,
          const float* __restrict__ W2, const float* __restrict__ W3,
          const float* __restrict__ Z,
          const int* __restrict__ c2b, const int* __restrict__ sidx,
          __hip_bfloat16* __restrict__ w1p, __hip_bfloat16* __restrict__ w2p,
          __hip_bfloat16* __restrict__ w3p, float* __restrict__ zw1,
          float* __restrict__ cnts, int* __restrict__ c2s) {
    int bid = blockIdx.x;
    int tid = threadIdx.x;
    if (bid < W1_BLKS + W2_BLKS + W3_BLKS) {
        const float* W; __hip_bfloat16* dst; int N, kS, idx; float scale;
        if (bid < W1_BLKS) {
            idx = bid * 256 + tid; W = W1; dst = w1p; N = H_DIM; kS = 4;
            scale = 0.6931471805599453f;          // ln2: staging uses log2
        } else if (bid < W1_BLKS + W2_BLKS) {
            idx = (bid - W1_BLKS) * 256 + tid; W = W2; dst = w2p; N = H_DIM; kS = 8;
            scale = 1.0f;
        } else {
            idx = (bid - W1_BLKS - W2_BLKS) * 256 + tid; W = W3; dst = w3p; N = D_OUT; kS = 8;
            scale = 1.0f;
        }
        int j = idx & 7;
        int L = (idx >> 3) & 63;
        int s = (idx >> 9) % kS;
        int t = idx / (kS << 9);
        int k = s * 32 + ((L >> 4) << 3) + j;
        int n = t * 16 + (L & 15);
        dst[idx] = __float2bfloat16(W[(size_t)k * N + n] * scale);
        return;
    }
    bid -= W1_BLKS + W2_BLKS + W3_BLKS;
    if (bid < ZW_BLKS) {
        int s = bid;
        float a = b1[tid];
        const float* zr = Z + (size_t)s * D_Z;
        const float* wr = W1 + (size_t)D_X * H_DIM + tid;
#pragma unroll 8
        for (int k = 0; k < D_Z; ++k) a += zr[k] * wr[(size_t)k * H_DIM];
        zw1[(size_t)s * H_DIM + tid] = a;
        return;
    }
    bid -= ZW_BLKS;
    int i = bid * 256 + tid;
    if (i < N_CELLS) {
        int si = sidx[c2b[i]];
        c2s[i] = si;
        atomicAdd(&cnts[(size_t)(bid & (NREP - 1)) * B_SAMP + si], 1.0f);
    }
}

// 96 cells/block, 512 threads, 8 waves in N-EIGHTH layout: each wave owns 32
// N-columns over ALL 96 cells (acc[6 m-frags][2 n-frags] = 48 VGPR). Every
// weight fragment loaded from L2 exactly once per tile; per-cell weight
// traffic and barrier count are 2/3 of the M=64 version. Swizzled pow2 LDS
// (conflict-free by bank analysis; residual SQ_LDS_BANK_CONFLICT counts are
// inherent b128 multi-cycle serialization, not fixable aliasing).
// LDS 72.4KB -> 2 blocks/CU. GEMM3 = 12 balanced tasks (6 row-groups x 2
// K-halves) over 8 waves.
__global__ __launch_bounds__(512, 4)
void fused_mlp(const float* __restrict__ X, const int* __restrict__ c2b,
               const int* __restrict__ c2s, const float* __restrict__ b2,
               const float* __restrict__ b3,
               const __hip_bfloat16* __restrict__ w1p,
               const __hip_bfloat16* __restrict__ w2p,
               const __hip_bfloat16* __restrict__ w3p,
               const float* __restrict__ zw1,
               float* __restrict__ accs, float* __restrict__ cnts) {
    __shared__ __align__(16) short sX[M_TILE * LDA];   // xp; aliased as sP later
    __shared__ __align__(16) short sH[M_TILE][LDH];    // H0 then H1 (in-place)
    __shared__ int sSI[M_TILE];
    short (*xp)[LDA] = (short (*)[LDA])sX;
    float (*sP)[M_TILE][SP_LD] = (float (*)[M_TILE][SP_LD])sX;  // [2][96][20]=15.4KB < 24KB

    const int tid = threadIdx.x;
    const int w   = tid >> 6;     // wave 0..7 = N-eighth owner
    const int L   = tid & 63;
    const int q   = L >> 4;
    const int ln  = L & 15;
    const int wn  = w;            // 32 n-columns: [wn*32, wn*32+32)
    const int base = blockIdx.x * M_TILE;

    // ---- GEMM1 C-init: gather ZW1 rows (bias + Z-part precomputed) ----
    floatx4 acc[6][2];
#pragma unroll
    for (int mt = 0; mt < 6; ++mt) {
        int g = base + mt * 16 + ln; if (g >= N_CELLS) g = N_CELLS - 1;
        int cbm = c2b[g];
#pragma unroll
        for (int nt = 0; nt < 2; ++nt)
            acc[mt][nt] = *(const floatx4*)(zw1 + (size_t)cbm * H_DIM + wn * 32 + nt * 16 + q * 4);
    }
    float b3v = b3[tid & 15];

    // ---- stage Xp = log2(1+X) bf16 into xp (swizzled) ----
#pragma unroll
    for (int i = 0; i < 6; ++i) {
        int idx = tid + i * 512;          // 96 rows * 32 float4
        int row = idx >> 5, c4 = idx & 31;
        int gr = base + row; if (gr >= N_CELLS) gr = N_CELLS - 1;
        float4 v = *(const float4*)(X + (size_t)gr * D_X + c4 * 4);
        short4v pk;
        pk.x = bfb(__log2f(1.0f + v.x));
        pk.y = bfb(__log2f(1.0f + v.y));
        pk.z = bfb(__log2f(1.0f + v.z));
        pk.w = bfb(__log2f(1.0f + v.w));
        *(short4v*)&xp[row][SWZ(c4 * 4, row)] = pk;
    }
    if (tid < M_TILE) {
        int gr = base + tid; if (gr >= N_CELLS) gr = N_CELLS - 1;
        sSI[tid] = c2s[gr];
    }
    __syncthreads();                                            // B1: Xp ready

    // ---- GEMM1: relu(logX @ W1x + ZW1) -> sH (each wf loaded once/tile) ----
#pragma unroll
    for (int s = 0; s < 4; ++s) {
        short8 xv[6];
#pragma unroll
        for (int mt = 0; mt < 6; ++mt)
            xv[mt] = *(const short8*)&xp[mt * 16 + ln][SWZ(s * 32 + q * 8, ln)];
#pragma unroll
        for (int nt = 0; nt < 2; ++nt) {
            int t = wn * 2 + nt;
            short8 wf = *(const short8*)(w1p + (size_t)(((t * 4 + s) << 6) + L) * 8);
#pragma unroll
            for (int mt = 0; mt < 6; ++mt)
                acc[mt][nt] = __builtin_amdgcn_mfma_f32_16x16x32_bf16(wf, xv[mt], acc[mt][nt], 0, 0, 0);
        }
    }
#pragma unroll
    for (int mt = 0; mt < 6; ++mt)
#pragma unroll
        for (int nt = 0; nt < 2; ++nt) {
            short4v pk;
            pk.x = bfb(fmaxf(acc[mt][nt][0], 0.f));
            pk.y = bfb(fmaxf(acc[mt][nt][1], 0.f));
            pk.z = bfb(fmaxf(acc[mt][nt][2], 0.f));
            pk.w = bfb(fmaxf(acc[mt][nt][3], 0.f));
            *(short4v*)&sH[mt * 16 + ln][SWZ(wn * 32 + nt * 16 + q * 4, ln)] = pk;
        }
    __syncthreads();                                            // B2: H0 ready

    // ---- GEMM2: relu(H0 @ W2 + b2), in-place on sH ----
#pragma unroll
    for (int nt = 0; nt < 2; ++nt) {
        float4 bv = *(const float4*)(b2 + wn * 32 + nt * 16 + q * 4);
        floatx4 b = (floatx4){bv.x, bv.y, bv.z, bv.w};
#pragma unroll
        for (int mt = 0; mt < 6; ++mt) acc[mt][nt] = b;
    }
#pragma unroll
    for (int s = 0; s < 8; ++s) {
        short8 xv[6];
#pragma unroll
        for (int mt = 0; mt < 6; ++mt)
            xv[mt] = *(const short8*)&sH[mt * 16 + ln][SWZ(s * 32 + q * 8, ln)];
#pragma unroll
        for (int nt = 0; nt < 2; ++nt) {
            int t = wn * 2 + nt;
            short8 wf = *(const short8*)(w2p + (size_t)(((t * 8 + s) << 6) + L) * 8);
#pragma unroll
            for (int mt = 0; mt < 6; ++mt)
                acc[mt][nt] = __builtin_amdgcn_mfma_f32_16x16x32_bf16(wf, xv[mt], acc[mt][nt], 0, 0, 0);
        }
    }
    __syncthreads();                                            // B3: H0 reads done
#pragma unroll
    for (int mt = 0; mt < 6; ++mt)
#pragma unroll
        for (int nt = 0; nt < 2; ++nt) {
            short4v pk;
            pk.x = bfb(fmaxf(acc[mt][nt][0], 0.f));
            pk.y = bfb(fmaxf(acc[mt][nt][1], 0.f));
            pk.z = bfb(fmaxf(acc[mt][nt][2], 0.f));
            pk.w = bfb(fmaxf(acc[mt][nt][3], 0.f));
            *(short4v*)&sH[mt * 16 + ln][SWZ(wn * 32 + nt * 16 + q * 4, ln)] = pk;
        }
    __syncthreads();                                            // B4: H1 ready

    // ---- GEMM3: 12 tasks (g in 0..5, kh in 0..1) over 8 waves -> sP ----
#pragma unroll
    for (int r2 = 0; r2 < 2; ++r2) {
        int t = w + r2 * 8;
        if (t < 12) {
            int g  = t >> 1;
            int kh = t & 1;
            floatx4 a3 = (floatx4){0.f, 0.f, 0.f, 0.f};
#pragma unroll
            for (int ss = 0; ss < 4; ++ss) {
                int s = kh * 4 + ss;
                short8 hv = *(const short8*)&sH[g * 16 + ln][SWZ(s * 32 + q * 8, ln)];
                short8 wf = *(const short8*)(w3p + (size_t)((s << 6) + L) * 8);
                a3 = __builtin_amdgcn_mfma_f32_16x16x32_bf16(wf, hv, a3, 0, 0, 0);
            }
            *(floatx4*)&sP[kh][g * 16 + ln][q * 4] = a3;   // xp reads ended pre-B2
        }
    }
    __syncthreads();                                            // B5: sP ready

    // ---- combine K-halves + b3, staged coalesced atomics ----
    {
        int rep = blockIdx.x & (NREP - 1);
        float* accR = accs + (size_t)rep * (B_SAMP * D_OUT);
#pragma unroll
        for (int i = 0; i < 3; ++i) {
            int idx = tid + i * 512;      // 96 cells x 16 outs
            int m = idx >> 4, n = idx & 15;
            int cell = base + m;
            if (cell < N_CELLS) {
                float v = sP[0][m][n] + sP[1][m][n] + b3v;
                atomicAdd(&accR[(size_t)sSI[m] * D_OUT + n], v);
            }
        }
    }
}

__global__ __launch_bounds__(256)
void finalize(const float* __restrict__ accs, const float* __restrict__ cnts,
              float* __restrict__ out) {
    int o = blockIdx.x * blockDim.x + threadIdx.x;   // 0..8191
    int s = o >> 4;
    float sum = 0.f, cnt = 0.f;
#pragma unroll 8
    for (int r = 0; r < NREP; ++r) {
        sum += accs[(size_t)r * (B_SAMP * D_OUT) + o];
        cnt += cnts[(size_t)r * B_SAMP + s];
    }
    out[o] = sum / fmaxf(cnt, 1.0f);
}

extern "C" void kernel_launch(void* const* d_in, const int* in_sizes, int n_in,
                              void* d_out, int out_size, void* d_ws, size_t ws_size,
                              hipStream_t stream) {
    const float* X   = (const float*)d_in[0];
    const float* Z   = (const float*)d_in[1];
    const float* W1  = (const float*)d_in[2];
    const float* b1  = (const float*)d_in[3];
    const float* W2  = (const float*)d_in[4];
    const float* b2  = (const float*)d_in[5];
    const float* W3  = (const float*)d_in[6];
    const float* b3  = (const float*)d_in[7];
    const int*   c2b = (const int*)d_in[8];
    const int*   sidx= (const int*)d_in[9];

    char* ws = (char*)d_ws;
    __hip_bfloat16* w1p = (__hip_bfloat16*)(ws + OFF_W1P);
    __hip_bfloat16* w2p = (__hip_bfloat16*)(ws + OFF_W2P);
    __hip_bfloat16* w3p = (__hip_bfloat16*)(ws + OFF_W3P);
    float* zw1  = (float*)(ws + OFF_ZW);
    float* accs = (float*)(ws + OFF_ACC);
    float* cnts = (float*)(ws + OFF_CNT);
    int*   c2s  = (int*)(ws + OFF_C2S);
    float* out  = (float*)d_out;

    // zero accs+cnts (contiguous); stream-ordered, graph-capture-safe
    hipMemsetAsync(accs, 0, (size_t)NREP * (B_SAMP * D_OUT + B_SAMP) * 4, stream);

    prep<<<W1_BLKS + W2_BLKS + W3_BLKS + ZW_BLKS + C2S_BLKS, 256, 0, stream>>>(
        W1, b1, W2, W3, Z, c2b, sidx, w1p, w2p, w3p, zw1, cnts, c2s);

    fused_mlp<<<NBLK, 512, 0, stream>>>(X, c2b, c2s, b2, b3,
                                        w1p, w2p, w3p, zw1, accs, cnts);
    finalize<<<32, 256, 0, stream>>>(accs, cnts, out);
}